// Round 1
// baseline (313.520 us; speedup 1.0000x reference)
//
#include <hip/hip_runtime.h>
#include <math.h>

// Problem constants (match reference)
#define Bb   16
#define Cc   3
#define Hh   64
#define Ww   64
#define Kk   32
#define Ss   32
#define OHh  60
#define OWw  60
#define Pp   3600
#define XROW 65            // padded LDS row stride (bank-conflict fix: 65 mod 32 = 1)
#define XCH  (64 * XROW)   // floats per channel in LDS = 4160
#define NGRP 900           // 60 rows * 15 groups of 4 columns

// coef layout: x=c0, y=dA(=c2-c0), z=dB(=c1-c0), w=dAB(=c0-c1-c2+c3)
// combine: y = c0 + a*dA + b*dB + a*b*dAB
__device__ __forceinline__ float4 combine4(const float4 a, const float4 b, const float4 c) {
    float4 r;
    r.x = fmaf(a.x, fmaf(b.x, c.w, c.y), fmaf(b.x, c.z, c.x));
    r.y = fmaf(a.y, fmaf(b.y, c.w, c.y), fmaf(b.y, c.z, c.x));
    r.z = fmaf(a.z, fmaf(b.z, c.w, c.y), fmaf(b.z, c.z, c.x));
    r.w = fmaf(a.w, fmaf(b.w, c.w, c.y), fmaf(b.w, c.z, c.x));
    return r;
}

__global__ __launch_bounds__(256, 2) void logic_conv_kernel(
    const float* __restrict__ x,
    const int*   __restrict__ h_idx,
    const int*   __restrict__ w_idx,
    const int*   __restrict__ c_idx,
    const float* __restrict__ w0, const float* __restrict__ w1,
    const float* __restrict__ w2, const float* __restrict__ w3,
    const float* __restrict__ w4, const float* __restrict__ w5,
    float* __restrict__ out)
{
    __shared__ float  xs[Cc * XCH];     // 3*4160*4 = 49,920 B
    __shared__ float4 coefs[63];        // 1,008 B
    __shared__ int2   bases[32];        // 256 B

    const int tid = threadIdx.x;
    const int blk = blockIdx.x;
    const int b   = blk >> 5;           // / K
    const int k   = blk & 31;           // % K

    // ---- stage x[b] into padded LDS (12288 floats, float4 global reads) ----
    const float* xb = x + b * (Cc * Hh * Ww);
    #pragma unroll
    for (int it = 0; it < 12; ++it) {
        const int f = (it * 256 + tid) * 4;           // flat index, 16B-aligned
        const float4 v = *reinterpret_cast<const float4*>(xb + f);
        const int c   = f >> 12;                      // / 4096
        const int rem = f & 4095;
        const int h   = rem >> 6;
        const int w   = rem & 63;
        float* d = &xs[c * XCH + h * XROW + w];
        d[0] = v.x; d[1] = v.y; d[2] = v.z; d[3] = v.w;
    }

    // ---- gather bases: LDS offsets for each leaf's two inputs ----
    if (tid < 32) {
        const int i0 = (0 * Kk + k) * Ss + tid;
        const int i1 = (1 * Kk + k) * Ss + tid;
        bases[tid] = make_int2(
            c_idx[i0] * XCH + h_idx[i0] * XROW + w_idx[i0],
            c_idx[i1] * XCH + h_idx[i1] * XROW + w_idx[i1]);
    }

    // ---- per-node coefficients: softmax(w)/LUT folded to 4 floats ----
    if (tid < 63) {
        const float* wp; int n;
        if      (tid < 32) { wp = w0; n = tid;      }
        else if (tid < 48) { wp = w1; n = tid - 32; }
        else if (tid < 56) { wp = w2; n = tid - 48; }
        else if (tid < 60) { wp = w3; n = tid - 56; }
        else if (tid < 62) { wp = w4; n = tid - 60; }
        else               { wp = w5; n = 0;        }
        const float* lg = wp + (n * Kk + k) * 16;
        float l[16];
        float m = lg[0];
        #pragma unroll
        for (int t = 0; t < 16; ++t) { l[t] = lg[t]; m = fmaxf(m, l[t]); }
        float e[16], s = 0.f;
        #pragma unroll
        for (int t = 0; t < 16; ++t) { e[t] = __expf(l[t] - m); s += e[t]; }
        const float inv = 1.f / s;
        float c0 = 0.f, c1 = 0.f, c2 = 0.f, c3 = 0.f;
        #pragma unroll
        for (int op = 0; op < 16; ++op) {
            if (op & 1) c0 += e[op];   // t=0
            if (op & 2) c1 += e[op];   // t=1
            if (op & 4) c2 += e[op];   // t=2
            if (op & 8) c3 += e[op];   // t=3
        }
        c0 *= inv; c1 *= inv; c2 *= inv; c3 *= inv;
        coefs[tid] = make_float4(c0, c2 - c0, c1 - c0, c0 - c1 - c2 + c3);
    }

    __syncthreads();

    // ---- main loop: each thread does groups of 4 consecutive output cols ----
    float* outp = out + blk * Pp;
    for (int g = tid; g < NGRP; g += 256) {
        const int oh  = g / 15;
        const int ow0 = (g - oh * 15) << 2;
        const int off = oh * XROW + ow0;

        float4 y2[8];
        #pragma unroll
        for (int m2 = 0; m2 < 8; ++m2) {
            float4 y1[2];
            #pragma unroll
            for (int m1 = 0; m1 < 2; ++m1) {
                float4 y0[2];
                #pragma unroll
                for (int m0 = 0; m0 < 2; ++m0) {
                    const int n = m2 * 4 + m1 * 2 + m0;      // leaf 0..31
                    const int2 bn = bases[n];
                    const float* pa = &xs[bn.x + off];
                    const float* pb = &xs[bn.y + off];
                    const float4 a  = make_float4(pa[0], pa[1], pa[2], pa[3]);
                    const float4 bv = make_float4(pb[0], pb[1], pb[2], pb[3]);
                    y0[m0] = combine4(a, bv, coefs[n]);
                }
                y1[m1] = combine4(y0[0], y0[1], coefs[32 + m2 * 2 + m1]);
            }
            y2[m2] = combine4(y1[0], y1[1], coefs[48 + m2]);
        }
        float4 y3[4];
        #pragma unroll
        for (int m = 0; m < 4; ++m) y3[m] = combine4(y2[2*m], y2[2*m+1], coefs[56 + m]);
        float4 y4[2];
        #pragma unroll
        for (int m = 0; m < 2; ++m) y4[m] = combine4(y3[2*m], y3[2*m+1], coefs[60 + m]);
        const float4 y5 = combine4(y4[0], y4[1], coefs[62]);

        *reinterpret_cast<float4*>(outp + oh * OWw + ow0) = y5;
    }
}

extern "C" void kernel_launch(void* const* d_in, const int* in_sizes, int n_in,
                              void* d_out, int out_size, void* d_ws, size_t ws_size,
                              hipStream_t stream) {
    const float* x     = (const float*)d_in[0];
    const int*   h_idx = (const int*)d_in[1];
    const int*   w_idx = (const int*)d_in[2];
    const int*   c_idx = (const int*)d_in[3];
    const float* w0    = (const float*)d_in[4];
    const float* w1    = (const float*)d_in[5];
    const float* w2    = (const float*)d_in[6];
    const float* w3    = (const float*)d_in[7];
    const float* w4    = (const float*)d_in[8];
    const float* w5    = (const float*)d_in[9];
    float* out = (float*)d_out;

    dim3 grid(Bb * Kk);   // 512 blocks: one per (b, k)
    dim3 block(256);
    hipLaunchKernelGGL(logic_conv_kernel, grid, block, 0, stream,
                       x, h_idx, w_idx, c_idx, w0, w1, w2, w3, w4, w5, out);
}